// Round 1
// baseline (530.436 us; speedup 1.0000x reference)
//
#include <hip/hip_runtime.h>

// SpikingNN LIF scan: N=131072 traces x L=401 timesteps, fp32.
// Thread-per-trace, LDS-staged tiles for coalesced global access.
// Constants from reference: D=0.25, PSPIKE=4, PTH=25, PMIN=-1, PREF=0,
// TREF=5, DT=0.125. Pn input is never read (dead in reference).

#define N_TRACES 131072
#define L_STEPS  401
#define BLK      256
#define CHUNK    32          // timesteps per LDS tile
#define LDS_PITCH (CHUNK + 1) // +1 pad -> bank (tid+j)%32, conflict-free

__global__ __launch_bounds__(BLK) void snn_scan_kernel(
    const float* __restrict__ S, float* __restrict__ out)
{
    __shared__ float tile[BLK * LDS_PITCH];

    const int tid  = threadIdx.x;
    const int base = blockIdx.x * BLK;           // first trace of this block
    const int rowS = base * L_STEPS;             // fits in int32 (52.6M max)

    float P      = 0.0f;   // carry: membrane potential (prev step's output)
    float t_rest = 0.0f;   // carry: refractory deadline

    for (int c0 = 0; c0 < L_STEPS; c0 += CHUNK) {
        const int ncol = min(CHUNK, L_STEPS - c0);

        // ---- coalesced load: [256 traces][ncol steps] tile ----
        // idx = k*256+tid -> row=idx/32, col=idx%32; consecutive lanes hit
        // consecutive addresses within a row (32 lanes = 128B segment).
        #pragma unroll
        for (int k = 0; k < CHUNK; ++k) {
            const int idx = k * BLK + tid;
            const int row = idx >> 5;            // / CHUNK
            const int col = idx & (CHUNK - 1);   // % CHUNK
            if (col < ncol) {
                tile[row * LDS_PITCH + col] = S[rowS + row * L_STEPS + c0 + col];
            }
        }
        __syncthreads();

        // ---- sequential scan on this thread's own LDS row (in place) ----
        float* myrow = &tile[tid * LDS_PITCH];
        for (int j = 0; j < ncol; ++j) {
            const int   i = c0 + j;
            const float t = (float)i * 0.125f;   // exact in fp32
            const float s = myrow[j];
            float p;
            if (i == 0) {
                p = s - 0.25f;                   // P0 = S[:,0] - D
            } else {
                // refractory -> Pref(0); else integrate if P>Pmin else reset
                p = (t <= t_rest) ? 0.0f
                                  : ((P > -1.0f) ? ((P + s) - 0.25f) : 0.0f);
            }
            if (p >= 25.0f) {                    // spike: overshoot marker
                p += 4.0f;
                t_rest = t + 5.0f;               // exact in fp32
            }
            myrow[j] = p;
            P = p;
        }
        __syncthreads();

        // ---- coalesced store (mirror of load) ----
        #pragma unroll
        for (int k = 0; k < CHUNK; ++k) {
            const int idx = k * BLK + tid;
            const int row = idx >> 5;
            const int col = idx & (CHUNK - 1);
            if (col < ncol) {
                out[rowS + row * L_STEPS + c0 + col] = tile[row * LDS_PITCH + col];
            }
        }
        __syncthreads();
    }
}

extern "C" void kernel_launch(void* const* d_in, const int* in_sizes, int n_in,
                              void* d_out, int out_size, void* d_ws, size_t ws_size,
                              hipStream_t stream)
{
    // d_in[0] = Pn (never read by reference), d_in[1] = S
    const float* S   = (const float*)d_in[1];
    float*       out = (float*)d_out;

    const int blocks = N_TRACES / BLK;  // 512
    snn_scan_kernel<<<blocks, BLK, 0, stream>>>(S, out);
}

// Round 2
// 529.183 us; speedup vs baseline: 1.0024x; 1.0024x over previous
//
#include <hip/hip_runtime.h>

// SpikingNN LIF scan: N=131072 traces x L=401 steps, fp32. Bit-exact vs ref.
//
// Round-2 design:
//  - Wave-private everything: wave w owns rows [64w, 64w+64) of its block's
//    256 traces; stage/compute/store never cross waves -> ZERO barriers
//    (same-wave DS ops are in-order; no __syncthreads vmcnt(0) drains).
//  - XOR-swizzled LDS tile (slot = col ^ (row&31)): conflict-free on staging
//    writes, compute reads, and store reads. No padding.
//  - Fully unrolled compile-time loops (CHUNK=32): the 32 ds_reads batch-issue
//    instead of one dependent ds_read per 120-cycle round trip.
//  - 1-chunk-deep software pipeline (T14): issue chunk c+1's coalesced loads
//    into regs before computing chunk c; ds_write them after the store phase.
//  - i==0 special case removed: P=0, t_rest=-1 makes the general step produce
//    P0 = S[:,0]-D exactly (0 <= -1 false, 0 > -1 true).
// All arithmetic is add/sub/compare in ref order -> no FMA contraction, exact.

#define NT    131072
#define L     401
#define BLKT  256
#define CHUNK 32
#define NCH   13      // 12 full chunks + tail of 17 cols

__global__ __launch_bounds__(BLKT) void snn_scan_kernel(
    const float* __restrict__ S, float* __restrict__ out)
{
    __shared__ float smem[2][BLKT * CHUNK];   // 2 x 32 KB ping-pong (64 KB)

    const int tid  = threadIdx.x;
    const int lane = tid & 63;
    const int wave = tid >> 6;        // 0..3
    const int l5   = lane >> 5;       // 0/1: which of the 2 rows per k
    const int c5   = lane & 31;       // column within the 32-wide window
    const int tkey = tid & 31;        // swizzle key of this thread's own row

    const int rowBase = blockIdx.x * BLKT;  // first global trace of block
    const int wRow    = wave * 64;          // wave's first row (block-local)

    // ---- prologue: stage chunk 0 (cols 0..31) into smem[0] ----
    {
        float pre[CHUNK];
        #pragma unroll
        for (int k = 0; k < CHUNK; ++k) {
            const int riw = 2 * k + l5;                       // row-in-wave
            pre[k] = S[(rowBase + wRow + riw) * L + c5];      // coalesced
        }
        #pragma unroll
        for (int k = 0; k < CHUNK; ++k) {
            const int riw = 2 * k + l5;
            smem[0][(wRow + riw) * CHUNK + (c5 ^ (riw & 31))] = pre[k];
        }
    }

    float P = 0.0f, t_rest = -1.0f;   // folds the i==0 branch into the step

    #pragma unroll 1
    for (int cc = 0; cc < NCH; ++cc) {
        const int c0 = cc * CHUNK;
        float* __restrict__ bcur = smem[cc & 1];
        float* __restrict__ bnxt = smem[(cc + 1) & 1];

        // ---- (1) issue chunk cc+1 prefetch loads (coalesced, into regs) ----
        float pre[CHUNK];
        const bool have_next = (cc + 1 < NCH);
        if (have_next) {
            const int c0n = c0 + CHUNK;
            #pragma unroll
            for (int k = 0; k < CHUNK; ++k) {
                const int riw = 2 * k + l5;
                pre[k] = (c0n + c5 < L)
                       ? S[(rowBase + wRow + riw) * L + c0n + c5]
                       : 0.0f;                    // tail: masked slots = 0
            }
        }
        asm volatile("" ::: "memory");  // pin: don't sink prefetch issue

        // ---- (2) compute: batch-read own row (swizzled), LIF, write back ----
        float s[CHUNK];
        #pragma unroll
        for (int j = 0; j < CHUNK; ++j)
            s[j] = bcur[tid * CHUNK + (j ^ tkey)];

        float r[CHUNK];
        #pragma unroll
        for (int j = 0; j < CHUNK; ++j) {
            const float t = (float)(c0 + j) * 0.125f;   // exact in fp32
            float p = (t <= t_rest)
                    ? 0.0f
                    : ((P > -1.0f) ? (P + s[j]) - 0.25f : 0.0f);
            const bool spike = (p >= 25.0f);
            p      = spike ? p + 4.0f : p;       // overshoot marker
            t_rest = spike ? t + 5.0f : t_rest;  // refractory deadline (exact)
            r[j] = p;
            P    = p;
        }
        #pragma unroll
        for (int j = 0; j < CHUNK; ++j)
            bcur[tid * CHUNK + (j ^ tkey)] = r[j];

        // ---- (3) store phase: wave-private transpose out of LDS ----
        #pragma unroll
        for (int k = 0; k < CHUNK; ++k) {
            const int riw = 2 * k + l5;
            const float v = bcur[(wRow + riw) * CHUNK + c5];
            const int col = c5 ^ (riw & 31);
            if (c0 + col < L)
                out[(rowBase + wRow + riw) * L + c0 + col] = v;  // coalesced
        }

        asm volatile("" ::: "memory");  // pin: stores issue before stage waits

        // ---- (4) stage prefetched chunk into the other buffer ----
        if (have_next) {
            #pragma unroll
            for (int k = 0; k < CHUNK; ++k) {
                const int riw = 2 * k + l5;
                bnxt[(wRow + riw) * CHUNK + (c5 ^ (riw & 31))] = pre[k];
            }
        }
    }
}

extern "C" void kernel_launch(void* const* d_in, const int* in_sizes, int n_in,
                              void* d_out, int out_size, void* d_ws, size_t ws_size,
                              hipStream_t stream)
{
    // d_in[0] = Pn (dead in reference), d_in[1] = S
    const float* S   = (const float*)d_in[1];
    float*       out = (float*)d_out;

    snn_scan_kernel<<<NT / BLKT, BLKT, 0, stream>>>(S, out);
}